// Round 24
// baseline (78.843 us; speedup 1.0000x reference)
//
#include <hip/hip_runtime.h>

// Actor MLP, B=262144 rows, fp32 in/out. All three GEMM stages on MFMA.
// R24 = R23 + cross-tile software pipelining: 2 tiles (2x64 rows) per block,
// two 16KB LDS buffers. Tile-B's x staging (HBM load + cvt + ds_write) is
// issued right after tile-A's bar1 and hides under A's phase2+zstage+phase3.
// Weight frags hoisted ONCE for both tiles. Per-tile structure = R23
// (s aliased into x slice0 in place, z in C/D-native tiles + tr_b16 reads).

typedef float f4v  __attribute__((ext_vector_type(4)));
typedef short s8v  __attribute__((ext_vector_type(8)));
typedef _Float16 h8v __attribute__((ext_vector_type(8)));
typedef unsigned u2v __attribute__((ext_vector_type(2)));
typedef unsigned u4v __attribute__((ext_vector_type(4)));

constexpr int NG = 14, GI = 9, FH = 128, AD = 15;

__device__ __forceinline__ unsigned short f2bf(float f) {
    unsigned u = __builtin_bit_cast(unsigned, f);
    return (unsigned short)((u + 0x7fffu + ((u >> 16) & 1u)) >> 16);
}
__device__ __forceinline__ float bf2f(unsigned short h) {
    return __builtin_bit_cast(float, (unsigned)h << 16);
}
__device__ __forceinline__ f4v load4u(const float* p) {
    f4v v; __builtin_memcpy(&v, p, 16); return v;
}
__device__ __forceinline__ unsigned pkh(float a, float b) {
    return __builtin_bit_cast(unsigned, __builtin_amdgcn_cvt_pkrtz(a, b));
}
__device__ __forceinline__ unsigned pkbf(float a, float b) {
    unsigned r;
    asm("v_cvt_pk_bf16_f32 %0, %1, %2" : "=v"(r) : "v"(a), "v"(b));
    return r;
}

// pk layout (shorts): W3h[0,8192) W3l[8192,16384) W4h[16384,20480)
// W4l[20480,24576) W1T[24576,25088) W2T[25088,25600)
__global__ void pack_kernel(const float* __restrict__ W3,
                            const float* __restrict__ W4,
                            const float* __restrict__ W1,
                            const float* __restrict__ W2,
                            unsigned short* __restrict__ pk) {
    unsigned short* W3h = pk;
    unsigned short* W3l = pk + 8192;
    unsigned short* W4h = pk + 16384;
    unsigned short* W4l = pk + 20480;
    int t = blockIdx.x * 256 + threadIdx.x;
    if (t < 8192) {
        int j = t & 7, l = (t >> 3) & 63, nt = (t >> 9) & 7, kt = t >> 12;
        int k = kt * 32 + (l >> 4) * 8 + j, n = nt * 16 + (l & 15);
        float v = (k < 57) ? W3[k * FH + n] : 0.f;
        unsigned short h = f2bf(v);
        W3h[t] = h;
        W3l[t] = f2bf(v - bf2f(h));
    }
    if (t < 4096) {
        int j = t & 7, l = (t >> 3) & 63, nt = (t >> 9) & 1, kt = t >> 10;
        int k = kt * 32 + (l >> 4) * 8 + j, n = nt * 16 + (l & 15);
        float v = (n < 30) ? W4[k * 30 + n] : 0.f;
        unsigned short h = f2bf(v);
        W4h[t] = h;
        W4l[t] = f2bf(v - bf2f(h));
    }
    if (t < 512) {   // W1T/W2T A-frags
        int l = t >> 3, j = t & 7;
        int p = l >> 4, m = l & 15;
        float v1 = 0.f;
        if (p == 0 && j < 4)       v1 = W1[j * 16 + m];
        else if (p == 0 && j == 4) v1 = W1[8 * 16 + m];
        else if (p == 1 && j < 4)  v1 = W1[(4 + j) * 16 + m];
        int k2 = (j < 4) ? (p * 4 + j) : 99;
        float v2 = (k2 < 16 && m < 4) ? W2[k2 * 4 + m] : 0.f;
        _Float16 h1 = (_Float16)v1, h2 = (_Float16)v2;
        pk[24576 + t] = __builtin_bit_cast(unsigned short, h1);
        pk[25088 + t] = __builtin_bit_cast(unsigned short, h2);
    }
}

__global__ __launch_bounds__(256, 4) void actor_fused(
    const float* __restrict__ x,     // [B,126]
    const float* __restrict__ sale,  // [B,1]
    const float* __restrict__ b1,    // [16]
    const float* __restrict__ b2,    // [4]
    const float* __restrict__ b3,    // [128]
    const float* __restrict__ b4,    // [30]
    const unsigned short* __restrict__ pk,
    float* __restrict__ om, float* __restrict__ os)
{
    // Two 16KB buffers, one per tile. Per buffer (three lives, as R23):
    //  1. x fp16 slices (k0-3 + k8 g0-7 | k4-7 + k8 g8-13), 128B swz rows
    //  2. s bf16 in-place in slice0
    //  3. z bf16 C/D-tiled (after bar2a)
    __shared__ unsigned short xz[16384];   // 32768 B

    const int tid  = threadIdx.x;
    const int wv   = __builtin_amdgcn_readfirstlane(tid >> 6);  // wave 0..3
    const int lane = tid & 63;
    const int row0 = blockIdx.x * 128;
    const int p    = lane >> 4;
    const int col  = lane & 15;

    // ---- hoisted weights/biases (once for both tiles) ----
    const h8v w1t = __builtin_bit_cast(h8v, *(const s8v*)(pk + 24576 + lane * 8));
    const h8v w2t = __builtin_bit_cast(h8v, *(const s8v*)(pk + 25088 + lane * 8));
    const f4v b1f = load4u(b1 + p * 4);
    const f4v b2f = load4u(b2);
    const s8v* W3hv = (const s8v*)pk;
    const s8v* W3lv = (const s8v*)(pk + 8192);
    s8v bh[2][2], bl[2][2];
    #pragma unroll
    for (int kt = 0; kt < 2; ++kt)
        #pragma unroll
        for (int ntl = 0; ntl < 2; ++ntl) {
            int nt = 2 * wv + ntl;
            bh[kt][ntl] = W3hv[(kt * 8 + nt) * 64 + lane];
            bl[kt][ntl] = W3lv[(kt * 8 + nt) * 64 + lane];
        }
    const float bv0 = b3[32 * wv + col];
    const float bv1 = b3[32 * wv + 16 + col];
    const s8v* W4hv = (const s8v*)(pk + 16384);
    const s8v* W4lv = (const s8v*)(pk + 20480);
    const int mq   = __builtin_amdgcn_readfirstlane(wv >> 1);
    const int nq   = __builtin_amdgcn_readfirstlane(wv & 1);
    const int ocol = nq * 16 + col;
    s8v wh[4], wl[4];
    #pragma unroll
    for (int kt = 0; kt < 4; ++kt) {
        wh[kt] = W4hv[(kt * 2 + nq) * 64 + lane];
        wl[kt] = W4lv[(kt * 2 + nq) * 64 + lane];
    }
    const float b4i = (ocol < 30) ? b4[ocol] : 0.f;

    const int r1  = 16 * wv + col;
    const int ssw = (r1 & 7) << 4;
    const float svA = sale[row0 + r1];
    const float svB = sale[row0 + 64 + r1];

    f4v acc[4][2];

    // ---- wave-private x stage into buf: 224 (row,g) units per wave ----
    auto stage = [&](unsigned short* buf, int trow0) {
        char* bb = (char*)buf;
        const float* xw0 = x + (size_t)(trow0 + 16 * wv) * (NG * GI);
        #pragma unroll
        for (int i = 0; i < 4; ++i) {
            int unit = i * 64 + lane;
            if (i < 3 || lane < 32) {
                int rl = (unit * 149797) >> 21;  // unit / 14
                int g  = unit - rl * 14;
                const float* xs = xw0 + rl * 126 + g * 9;
                f4v a = load4u(xs);
                f4v b = load4u(xs + 4);
                float c = xs[8];
                int r  = 16 * wv + rl;
                int sw = (r & 7) << 4;
                int rb = r * 128;
                *(u2v*)(bb + (rb + ((g * 8) ^ sw))) =
                    (u2v){pkh(a[0], a[1]), pkh(a[2], a[3])};
                *(u2v*)(bb + 8192 + (rb + ((g * 8) ^ sw))) =
                    (u2v){pkh(b[0], b[1]), pkh(b[2], b[3])};
                _Float16 ch = (_Float16)c;
                int k8off = (g < 8 ? 0 : 8192) + rb + ((112 + (g & 7) * 2) ^ sw);
                *(unsigned short*)(bb + k8off) =
                    __builtin_bit_cast(unsigned short, ch);
            }
        }
    };

    // ---- phase 1: virtual-row MFMA; s written in place into slice0 ----
    auto phase1 = [&](unsigned short* buf, float sv) {
        char* xzb = (char*)buf;
        const char* xrow = xzb + (p ? 8192 : 0) + r1 * 128;
        const u4v k8A = *(const u4v*)(xzb + r1 * 128 + (112 ^ ssw));
        const u4v k8B = *(const u4v*)(xzb + 8192 + r1 * 128 + (112 ^ ssw));
        if (p == 0) {
            *(u4v*)(xzb + r1 * 128 + (112 ^ ssw)) =
                (u4v){(unsigned)f2bf(sv), 0u, 0u, 0u};
        }
        const int sbase = r1 * 128;
        #pragma unroll
        for (int gp = 0; gp < 7; ++gp) {
            u4v dv = *(const u4v*)(xrow + ((gp * 16) ^ ssw));
            unsigned sq[4];
            #pragma unroll
            for (int gi = 0; gi < 2; ++gi) {
                const int g = 2 * gp + gi;
                unsigned wk = (g < 8) ? k8A[g >> 1] : k8B[(g - 8) >> 1];
                unsigned k8v = (g & 1) ? (wk >> 16) : (wk & 0xffffu);
                h8v xb = __builtin_bit_cast(h8v,
                    (u4v){dv[2 * gi], dv[2 * gi + 1], k8v, 0u});
                f4v ha = __builtin_amdgcn_mfma_f32_16x16x32_f16(w1t, xb, b1f, 0, 0, 0);
                float h0 = fmaxf(ha[0], 0.f), h1 = fmaxf(ha[1], 0.f);
                float h2 = fmaxf(ha[2], 0.f), h3 = fmaxf(ha[3], 0.f);
                h8v hb = __builtin_bit_cast(h8v,
                    (u4v){pkh(h0, h1), pkh(h2, h3), 0u, 0u});
                f4v sa = __builtin_amdgcn_mfma_f32_16x16x32_f16(w2t, hb, b2f, 0, 0, 0);
                float s0 = fmaxf(sa[0], 0.f), s1 = fmaxf(sa[1], 0.f);
                float s2 = fmaxf(sa[2], 0.f), s3 = fmaxf(sa[3], 0.f);
                sq[2 * gi]     = pkbf(s0, s1);
                sq[2 * gi + 1] = pkbf(s2, s3);
            }
            if (p == 0) {
                *(u4v*)(xzb + (sbase + ((gp * 16) ^ ssw))) =
                    (u4v){sq[0], sq[1], sq[2], sq[3]};
            }
        }
    };

    // ---- phase 2: z = s @ W3 into acc ----
    auto phase2 = [&](unsigned short* buf) {
        char* xzb = (char*)buf;
        #pragma unroll
        for (int mt = 0; mt < 4; ++mt) {
            acc[mt][0] = (f4v){bv0, bv0, bv0, bv0};
            acc[mt][1] = (f4v){bv1, bv1, bv1, bv1};
        }
        #pragma unroll
        for (int kt = 0; kt < 2; ++kt) {
            s8v ah[4];
            #pragma unroll
            for (int mt = 0; mt < 4; ++mt) {
                int rr = mt * 16 + col;
                int byt = (rr * 128 + kt * 64 + p * 16) ^ ((rr & 7) << 4);
                ah[mt] = *(const s8v*)(xzb + byt);
            }
            #pragma unroll
            for (int mt = 0; mt < 4; ++mt)
                #pragma unroll
                for (int ntl = 0; ntl < 2; ++ntl) {
                    acc[mt][ntl] = __builtin_amdgcn_mfma_f32_16x16x32_bf16(ah[mt], bh[kt][ntl], acc[mt][ntl], 0, 0, 0);
                    acc[mt][ntl] = __builtin_amdgcn_mfma_f32_16x16x32_bf16(ah[mt], bl[kt][ntl], acc[mt][ntl], 0, 0, 0);
                }
        }
    };

    // ---- z staging into C/D-native tiles ----
    auto zstage = [&](unsigned short* buf) {
        #pragma unroll
        for (int mt = 0; mt < 4; ++mt)
            #pragma unroll
            for (int ntl = 0; ntl < 2; ++ntl) {
                int kk  = ntl * 16 + col;
                int tau = (kk & 4) ? 4 + (kk >> 3) : (kk >> 3);
                int eidx = mt * 2048 + wv * 512 + tau * 64 + (kk & 3) * 16 + (p << 2);
                float v0 = fmaxf(acc[mt][ntl][0], 0.f);
                float v1 = fmaxf(acc[mt][ntl][1], 0.f);
                float v2 = fmaxf(acc[mt][ntl][2], 0.f);
                float v3 = fmaxf(acc[mt][ntl][3], 0.f);
                *(u2v*)(buf + eidx) = (u2v){pkbf(v0, v1), pkbf(v2, v3)};
            }
    };

    // ---- phase 3: out = z @ W4 via tr_b16 reads + epilogue ----
    auto phase3 = [&](unsigned short* buf, int trow0) {
        unsigned base = (unsigned)(size_t)buf + (unsigned)(2 * mq) * 4096u
                      + (unsigned)(lane * 8);
        u2v f0[4][2], f1[4][2];
        #pragma unroll
        for (int c = 0; c < 4; ++c) {
            unsigned a0 = base + c * 1024;
            unsigned a1 = a0 + 4096;
            asm volatile("ds_read_b64_tr_b16 %0, %1" : "=v"(f0[c][0]) : "v"(a0));
            asm volatile("ds_read_b64_tr_b16 %0, %1 offset:512" : "=v"(f0[c][1]) : "v"(a0));
            asm volatile("ds_read_b64_tr_b16 %0, %1" : "=v"(f1[c][0]) : "v"(a1));
            asm volatile("ds_read_b64_tr_b16 %0, %1 offset:512" : "=v"(f1[c][1]) : "v"(a1));
        }
        asm volatile("s_waitcnt lgkmcnt(0)" ::: "memory");
        __builtin_amdgcn_sched_barrier(0);
        f4v oa0 = (f4v){b4i, b4i, b4i, b4i};
        f4v oa1 = oa0;
        #pragma unroll
        for (int kt = 0; kt < 4; ++kt) {
            s8v z0 = __builtin_bit_cast(s8v,
                (u4v){f0[kt][0][0], f0[kt][0][1], f0[kt][1][0], f0[kt][1][1]});
            s8v z1 = __builtin_bit_cast(s8v,
                (u4v){f1[kt][0][0], f1[kt][0][1], f1[kt][1][0], f1[kt][1][1]});
            oa0 = __builtin_amdgcn_mfma_f32_16x16x32_bf16(z0, wh[kt], oa0, 0, 0, 0);
            oa0 = __builtin_amdgcn_mfma_f32_16x16x32_bf16(z0, wl[kt], oa0, 0, 0, 0);
            oa1 = __builtin_amdgcn_mfma_f32_16x16x32_bf16(z1, wh[kt], oa1, 0, 0, 0);
            oa1 = __builtin_amdgcn_mfma_f32_16x16x32_bf16(z1, wl[kt], oa1, 0, 0, 0);
        }
        #pragma unroll
        for (int mi = 0; mi < 2; ++mi) {
            f4v oa = mi ? oa1 : oa0;
            #pragma unroll
            for (int i = 0; i < 4; ++i) {
                int grow = trow0 + mq * 32 + mi * 16 + p * 4 + i;
                float v = oa[i];
                if (ocol < AD) {
                    float tc = fminf(fmaxf(v, -20.f), 20.f);
                    float e = __expf(2.f * tc);
                    om[(size_t)grow * AD + ocol] = (e - 1.f) / (e + 1.f);
                } else if (ocol < 2 * AD) {
                    os[(size_t)grow * AD + (ocol - AD)] = __expf(v);
                }
            }
        }
    };

    unsigned short* bufA = xz;
    unsigned short* bufB = xz + 8192;

    // ---- tile A ----
    stage(bufA, row0);
    phase1(bufA, svA);
    __syncthreads();                 // bar1(A): s(A) ready
    stage(bufB, row0 + 64);          // prefetch tile B (hides under A compute)
    phase2(bufA);
    __syncthreads();                 // bar2a(A): s(A) reads done
    zstage(bufA);
    __syncthreads();                 // bar2b(A): z(A) ready
    phase3(bufA, row0);

    // ---- tile B ----
    phase1(bufB, svB);
    __syncthreads();                 // bar1(B)
    phase2(bufB);
    __syncthreads();                 // bar2a(B)
    zstage(bufB);
    __syncthreads();                 // bar2b(B)
    phase3(bufB, row0 + 64);
}

extern "C" void kernel_launch(void* const* d_in, const int* in_sizes, int n_in,
                              void* d_out, int out_size, void* d_ws, size_t ws_size,
                              hipStream_t stream) {
    const float* x    = (const float*)d_in[0];
    const float* sale = (const float*)d_in[1];
    const float* W1   = (const float*)d_in[2];
    const float* b1   = (const float*)d_in[3];
    const float* W2   = (const float*)d_in[4];
    const float* b2   = (const float*)d_in[5];
    const float* W3   = (const float*)d_in[6];
    const float* b3   = (const float*)d_in[7];
    const float* W4   = (const float*)d_in[8];
    const float* b4   = (const float*)d_in[9];

    int B = in_sizes[1];                       // sale_predictions is [B,1]
    float* om = (float*)d_out;                 // action_mean flat [B*15]
    float* os = om + (size_t)B * AD;           // action_std  flat [B*15]
    unsigned short* pk = (unsigned short*)d_ws;  // 25600 shorts = 51.2 KB

    pack_kernel<<<32, 256, 0, stream>>>(W3, W4, W1, W2, pk);
    actor_fused<<<B / 128, 256, 0, stream>>>(x, sale, b1, b2, b3, b4,
                                             pk, om, os);
}

// Round 25
// 44.700 us; speedup vs baseline: 1.7638x; 1.7638x over previous
//
#include <hip/hip_runtime.h>

// Actor MLP, B=262144 rows, fp32 in/out. All three GEMM stages on MFMA.
// R25 = exact revert to R23 (best verified: 44.3us wall, no spill).
// R24 post-mortem: two-tile pipelining extended fragment lifetimes ->
// register spill (WRITE 114MB, 79us). The single-tile R23 shape sits just
// under the register ceiling; structure must not grow live state.
//  - s aliased INTO x-slice0 in place (same-lane RAW, lockstep-safe)
//  - z bf16 C/D-native tiles + ds_read_b64_tr_b16 phase-3 reads
//  - weight frags hoisted across barriers; 3 barriers; LDS 16384.

typedef float f4v  __attribute__((ext_vector_type(4)));
typedef short s8v  __attribute__((ext_vector_type(8)));
typedef _Float16 h8v __attribute__((ext_vector_type(8)));
typedef unsigned u2v __attribute__((ext_vector_type(2)));
typedef unsigned u4v __attribute__((ext_vector_type(4)));

constexpr int NG = 14, GI = 9, FH = 128, AD = 15;

__device__ __forceinline__ unsigned short f2bf(float f) {
    unsigned u = __builtin_bit_cast(unsigned, f);
    return (unsigned short)((u + 0x7fffu + ((u >> 16) & 1u)) >> 16);
}
__device__ __forceinline__ float bf2f(unsigned short h) {
    return __builtin_bit_cast(float, (unsigned)h << 16);
}
__device__ __forceinline__ f4v load4u(const float* p) {
    f4v v; __builtin_memcpy(&v, p, 16); return v;
}
__device__ __forceinline__ unsigned pkh(float a, float b) {
    return __builtin_bit_cast(unsigned, __builtin_amdgcn_cvt_pkrtz(a, b));
}
__device__ __forceinline__ unsigned pkbf(float a, float b) {
    unsigned r;
    asm("v_cvt_pk_bf16_f32 %0, %1, %2" : "=v"(r) : "v"(a), "v"(b));
    return r;
}

// pk layout (shorts): W3h[0,8192) W3l[8192,16384) W4h[16384,20480)
// W4l[20480,24576) W1T[24576,25088) W2T[25088,25600)
__global__ void pack_kernel(const float* __restrict__ W3,
                            const float* __restrict__ W4,
                            const float* __restrict__ W1,
                            const float* __restrict__ W2,
                            unsigned short* __restrict__ pk) {
    unsigned short* W3h = pk;
    unsigned short* W3l = pk + 8192;
    unsigned short* W4h = pk + 16384;
    unsigned short* W4l = pk + 20480;
    int t = blockIdx.x * 256 + threadIdx.x;
    if (t < 8192) {
        int j = t & 7, l = (t >> 3) & 63, nt = (t >> 9) & 7, kt = t >> 12;
        int k = kt * 32 + (l >> 4) * 8 + j, n = nt * 16 + (l & 15);
        float v = (k < 57) ? W3[k * FH + n] : 0.f;
        unsigned short h = f2bf(v);
        W3h[t] = h;
        W3l[t] = f2bf(v - bf2f(h));
    }
    if (t < 4096) {
        int j = t & 7, l = (t >> 3) & 63, nt = (t >> 9) & 1, kt = t >> 10;
        int k = kt * 32 + (l >> 4) * 8 + j, n = nt * 16 + (l & 15);
        float v = (n < 30) ? W4[k * 30 + n] : 0.f;
        unsigned short h = f2bf(v);
        W4h[t] = h;
        W4l[t] = f2bf(v - bf2f(h));
    }
    if (t < 512) {   // W1T/W2T A-frags
        int l = t >> 3, j = t & 7;
        int p = l >> 4, m = l & 15;
        // layer1: p0 j0-3 -> k=j; p0 j4 -> k=8; p1 j0-3 -> k=4+j; else 0.
        float v1 = 0.f;
        if (p == 0 && j < 4)       v1 = W1[j * 16 + m];
        else if (p == 0 && j == 4) v1 = W1[8 * 16 + m];
        else if (p == 1 && j < 4)  v1 = W1[(4 + j) * 16 + m];
        // layer2: kappa2(p,j) = 4p+j for j<4 (h-frag slot order), else 0.
        int k2 = (j < 4) ? (p * 4 + j) : 99;
        float v2 = (k2 < 16 && m < 4) ? W2[k2 * 4 + m] : 0.f;
        _Float16 h1 = (_Float16)v1, h2 = (_Float16)v2;
        pk[24576 + t] = __builtin_bit_cast(unsigned short, h1);
        pk[25088 + t] = __builtin_bit_cast(unsigned short, h2);
    }
}

__global__ __launch_bounds__(256, 4) void actor_fused(
    const float* __restrict__ x,     // [B,126]
    const float* __restrict__ sale,  // [B,1]
    const float* __restrict__ b1,    // [16]
    const float* __restrict__ b2,    // [4]
    const float* __restrict__ b3,    // [128]
    const float* __restrict__ b4,    // [30]
    const unsigned short* __restrict__ pk,
    float* __restrict__ om, float* __restrict__ os)
{
    // xz 16384 B, three lives:
    //  1. x fp16: slice0 [0,8192) k0-3 pairs + k8 g0-7 in slot7;
    //     slice1 [8192,16384) k4-7 pairs + k8 g8-13. 128B rows, XOR-swizzled.
    //  2. s bf16 (during phase 1): written in-place into slice0 (slots 0-6 =
    //     k0..55, slot 7 = sale + zero pad k56..63). Same row swizzle.
    //  3. z bf16 tiled (after bar2a): all 16384 B.
    __shared__ unsigned short xz[8192];

    const int tid  = threadIdx.x;
    const int wv   = __builtin_amdgcn_readfirstlane(tid >> 6);  // wave 0..3
    const int lane = tid & 63;
    const int row0 = blockIdx.x * 64;
    const int p    = lane >> 4;
    const int col  = lane & 15;
    char* xzb = (char*)xz;

    // ---- hoisted phase-1 A-frags + biases ----
    const h8v w1t = __builtin_bit_cast(h8v, *(const s8v*)(pk + 24576 + lane * 8));
    const h8v w2t = __builtin_bit_cast(h8v, *(const s8v*)(pk + 25088 + lane * 8));
    const f4v b1f = load4u(b1 + p * 4);
    const f4v b2f = load4u(b2);
    // ---- hoisted phase-2 weight B-frags + b3 (latency hides under phase 1) --
    const s8v* W3hv = (const s8v*)pk;
    const s8v* W3lv = (const s8v*)(pk + 8192);
    s8v bh[2][2], bl[2][2];
    #pragma unroll
    for (int kt = 0; kt < 2; ++kt)
        #pragma unroll
        for (int ntl = 0; ntl < 2; ++ntl) {
            int nt = 2 * wv + ntl;
            bh[kt][ntl] = W3hv[(kt * 8 + nt) * 64 + lane];
            bl[kt][ntl] = W3lv[(kt * 8 + nt) * 64 + lane];
        }
    const float bv0 = b3[32 * wv + col];
    const float bv1 = b3[32 * wv + 16 + col];

    // ---- wave-private x stage: 224 (row,g) units per wave ----
    {
        const float* xw0 = x + (size_t)(row0 + 16 * wv) * (NG * GI);
        #pragma unroll
        for (int i = 0; i < 4; ++i) {
            int unit = i * 64 + lane;
            if (i < 3 || lane < 32) {           // 224 units
                int rl = (unit * 149797) >> 21;  // unit / 14
                int g  = unit - rl * 14;
                const float* xs = xw0 + rl * 126 + g * 9;
                f4v a = load4u(xs);
                f4v b = load4u(xs + 4);
                float c = xs[8];
                int r  = 16 * wv + rl;
                int sw = (r & 7) << 4;
                int rb = r * 128;
                *(u2v*)(xzb + (rb + ((g * 8) ^ sw))) =
                    (u2v){pkh(a[0], a[1]), pkh(a[2], a[3])};
                *(u2v*)(xzb + 8192 + (rb + ((g * 8) ^ sw))) =
                    (u2v){pkh(b[0], b[1]), pkh(b[2], b[3])};
                _Float16 ch = (_Float16)c;
                int k8off = (g < 8 ? 0 : 8192) + rb + ((112 + (g & 7) * 2) ^ sw);
                *(unsigned short*)(xzb + k8off) =
                    __builtin_bit_cast(unsigned short, ch);
            }
        }
    }

    // ---- phase 1: virtual-row MFMA; wave wv owns rows 16wv..16wv+15 ----
    const int r1 = 16 * wv + col;
    const int ssw = (r1 & 7) << 4;
    const char* xrow = xzb + (p ? 8192 : 0) + r1 * 128;   // p>=2: garbage, A=0
    const float sv = sale[row0 + r1];
    // all 14 k8 values: slot 7 of both slices of row r1 (consumed here, then
    // slot 7 of slice0 is recycled for s k=56..63)
    const u4v k8A = *(const u4v*)(xzb + r1 * 128 + (112 ^ ssw));
    const u4v k8B = *(const u4v*)(xzb + 8192 + r1 * 128 + (112 ^ ssw));
    if (p == 0) {   // sale (k=56) + zero pad (k=57..63) into slice0 slot 7
        *(u4v*)(xzb + r1 * 128 + (112 ^ ssw)) =
            (u4v){(unsigned)f2bf(sv), 0u, 0u, 0u};
    }
    const int sbase = r1 * 128;

    #pragma unroll
    for (int gp = 0; gp < 7; ++gp) {
        u4v dv = *(const u4v*)(xrow + ((gp * 16) ^ ssw));   // ds_read_b128
        unsigned sq[4];   // two s-pairs for g=2gp, 2gp+1
        #pragma unroll
        for (int gi = 0; gi < 2; ++gi) {
            const int g = 2 * gp + gi;
            unsigned wk = (g < 8) ? k8A[g >> 1] : k8B[(g - 8) >> 1];
            unsigned k8v = (g & 1) ? (wk >> 16) : (wk & 0xffffu);
            h8v xb = __builtin_bit_cast(h8v,
                (u4v){dv[2 * gi], dv[2 * gi + 1], k8v, 0u});
            f4v ha = __builtin_amdgcn_mfma_f32_16x16x32_f16(w1t, xb, b1f, 0, 0, 0);
            float h0 = fmaxf(ha[0], 0.f), h1 = fmaxf(ha[1], 0.f);
            float h2 = fmaxf(ha[2], 0.f), h3 = fmaxf(ha[3], 0.f);
            h8v hb = __builtin_bit_cast(h8v,
                (u4v){pkh(h0, h1), pkh(h2, h3), 0u, 0u});
            f4v sa = __builtin_amdgcn_mfma_f32_16x16x32_f16(w2t, hb, b2f, 0, 0, 0);
            float s0 = fmaxf(sa[0], 0.f), s1 = fmaxf(sa[1], 0.f);
            float s2 = fmaxf(sa[2], 0.f), s3 = fmaxf(sa[3], 0.f);
            sq[2 * gi]     = pkbf(s0, s1);
            sq[2 * gi + 1] = pkbf(s2, s3);
        }
        // write s for g=2gp,2gp+1 back into slice0 slot gp (just read above;
        // p0 lane is this slot's only reader -> same-lane RAW, lockstep-safe)
        if (p == 0) {
            *(u4v*)(xzb + (sbase + ((gp * 16) ^ ssw))) =
                (u4v){sq[0], sq[1], sq[2], sq[3]};
        }
    }

    __syncthreads();   // bar 1: all s ready (s lives in slice0)

    // ---------------- phase 2: z[64,128] = s[64,64] @ W3  (MFMA) ----------
    f4v acc[4][2];
    #pragma unroll
    for (int mt = 0; mt < 4; ++mt) {
        acc[mt][0] = (f4v){bv0, bv0, bv0, bv0};
        acc[mt][1] = (f4v){bv1, bv1, bv1, bv1};
    }
    #pragma unroll
    for (int kt = 0; kt < 2; ++kt) {
        s8v ah[4];
        #pragma unroll
        for (int mt = 0; mt < 4; ++mt) {
            int rr = mt * 16 + col;
            int byt = (rr * 128 + kt * 64 + p * 16) ^ ((rr & 7) << 4);
            ah[mt] = *(const s8v*)(xzb + byt);
        }
        #pragma unroll
        for (int mt = 0; mt < 4; ++mt)
            #pragma unroll
            for (int ntl = 0; ntl < 2; ++ntl) {
                acc[mt][ntl] = __builtin_amdgcn_mfma_f32_16x16x32_bf16(ah[mt], bh[kt][ntl], acc[mt][ntl], 0, 0, 0);
                acc[mt][ntl] = __builtin_amdgcn_mfma_f32_16x16x32_bf16(ah[mt], bl[kt][ntl], acc[mt][ntl], 0, 0, 0);
            }
    }

    // ---- hoisted phase-3 weight B-frags + b4 (latency hides over bar2a) ----
    const s8v* W4hv = (const s8v*)(pk + 16384);
    const s8v* W4lv = (const s8v*)(pk + 20480);
    const int mq   = __builtin_amdgcn_readfirstlane(wv >> 1);  // row-half
    const int nq   = __builtin_amdgcn_readfirstlane(wv & 1);   // col-half
    const int ocol = nq * 16 + col;
    s8v wh[4], wl[4];
    #pragma unroll
    for (int kt = 0; kt < 4; ++kt) {
        wh[kt] = W4hv[(kt * 2 + nq) * 64 + lane];
        wl[kt] = W4lv[(kt * 2 + nq) * 64 + lane];
    }
    const float b4i = (ocol < 30) ? b4[ocol] : 0.f;

    __syncthreads();   // bar 2a: all s reads done; slice0 now reusable for z

    // stage relu(z) into C/D-native tiled layout (2 cvt_pk + b64 per frag)
    #pragma unroll
    for (int mt = 0; mt < 4; ++mt)
        #pragma unroll
        for (int ntl = 0; ntl < 2; ++ntl) {
            int kk  = ntl * 16 + col;               // K & 31 (chunk = wv)
            int tau = (kk & 4) ? 4 + (kk >> 3) : (kk >> 3);
            int eidx = mt * 2048 + wv * 512 + tau * 64 + (kk & 3) * 16 + (p << 2);
            float v0 = fmaxf(acc[mt][ntl][0], 0.f);
            float v1 = fmaxf(acc[mt][ntl][1], 0.f);
            float v2 = fmaxf(acc[mt][ntl][2], 0.f);
            float v3 = fmaxf(acc[mt][ntl][3], 0.f);
            *(u2v*)(xz + eidx) = (u2v){pkbf(v0, v1), pkbf(v2, v3)};
        }

    __syncthreads();   // bar 2b: z ready

    // ---- phase 3: out[64,30] = z @ W4; A-frags via ds_read_b64_tr_b16 ----
    unsigned base = (unsigned)(size_t)&xz[0] + (unsigned)(2 * mq) * 4096u
                  + (unsigned)(lane * 8);
    u2v f0[4][2], f1[4][2];
    #pragma unroll
    for (int c = 0; c < 4; ++c) {
        unsigned a0 = base + c * 1024;
        unsigned a1 = a0 + 4096;
        asm volatile("ds_read_b64_tr_b16 %0, %1" : "=v"(f0[c][0]) : "v"(a0));
        asm volatile("ds_read_b64_tr_b16 %0, %1 offset:512" : "=v"(f0[c][1]) : "v"(a0));
        asm volatile("ds_read_b64_tr_b16 %0, %1" : "=v"(f1[c][0]) : "v"(a1));
        asm volatile("ds_read_b64_tr_b16 %0, %1 offset:512" : "=v"(f1[c][1]) : "v"(a1));
    }
    asm volatile("s_waitcnt lgkmcnt(0)" ::: "memory");
    __builtin_amdgcn_sched_barrier(0);

    f4v oa0 = (f4v){b4i, b4i, b4i, b4i};
    f4v oa1 = oa0;
    #pragma unroll
    for (int kt = 0; kt < 4; ++kt) {
        s8v z0 = __builtin_bit_cast(s8v,
            (u4v){f0[kt][0][0], f0[kt][0][1], f0[kt][1][0], f0[kt][1][1]});
        s8v z1 = __builtin_bit_cast(s8v,
            (u4v){f1[kt][0][0], f1[kt][0][1], f1[kt][1][0], f1[kt][1][1]});
        oa0 = __builtin_amdgcn_mfma_f32_16x16x32_bf16(z0, wh[kt], oa0, 0, 0, 0);
        oa0 = __builtin_amdgcn_mfma_f32_16x16x32_bf16(z0, wl[kt], oa0, 0, 0, 0);
        oa1 = __builtin_amdgcn_mfma_f32_16x16x32_bf16(z1, wh[kt], oa1, 0, 0, 0);
        oa1 = __builtin_amdgcn_mfma_f32_16x16x32_bf16(z1, wl[kt], oa1, 0, 0, 0);
    }
    #pragma unroll
    for (int mi = 0; mi < 2; ++mi) {
        f4v oa = mi ? oa1 : oa0;
        #pragma unroll
        for (int i = 0; i < 4; ++i) {
            int grow = row0 + mq * 32 + mi * 16 + p * 4 + i;
            float v = oa[i];
            if (ocol < AD) {
                float tc = fminf(fmaxf(v, -20.f), 20.f);
                float e = __expf(2.f * tc);
                om[(size_t)grow * AD + ocol] = (e - 1.f) / (e + 1.f);
            } else if (ocol < 2 * AD) {
                os[(size_t)grow * AD + (ocol - AD)] = __expf(v);
            }
        }
    }
}

extern "C" void kernel_launch(void* const* d_in, const int* in_sizes, int n_in,
                              void* d_out, int out_size, void* d_ws, size_t ws_size,
                              hipStream_t stream) {
    const float* x    = (const float*)d_in[0];
    const float* sale = (const float*)d_in[1];
    const float* W1   = (const float*)d_in[2];
    const float* b1   = (const float*)d_in[3];
    const float* W2   = (const float*)d_in[4];
    const float* b2   = (const float*)d_in[5];
    const float* W3   = (const float*)d_in[6];
    const float* b3   = (const float*)d_in[7];
    const float* W4   = (const float*)d_in[8];
    const float* b4   = (const float*)d_in[9];

    int B = in_sizes[1];                       // sale_predictions is [B,1]
    float* om = (float*)d_out;                 // action_mean flat [B*15]
    float* os = om + (size_t)B * AD;           // action_std  flat [B*15]
    unsigned short* pk = (unsigned short*)d_ws;  // 25600 shorts = 51.2 KB

    pack_kernel<<<32, 256, 0, stream>>>(W3, W4, W1, W2, pk);
    actor_fused<<<B / 64, 256, 0, stream>>>(x, sale, b1, b2, b3, b4,
                                            pk, om, os);
}